// Round 4
// baseline (668.863 us; speedup 1.0000x reference)
//
#include <hip/hip_runtime.h>

#define EE      640000
#define NNODES_ 10000
#define NG      64
#define DN      128
#define DE      32
#define HID     128
#define DOUT    64
#define NMT     (EE / 16)
#define SLOWNB  768
#define FNB     768

// ---- workspace float-element offsets ----
#define ACCF  0        // [64][128] per-graph sum of a
#define CNTF  8192     // [64] edge count per graph (fp32)
#define S1F   8256     // [128] global sum(a)
#define S2F   8384     // [128] global sum(a^2)
#define GXF   8512     // [64][128] per-graph node sums
#define O1F   16704    // [64][128] mlp2 hidden
#define FLGF  24896    // int flags: [0]=floats-are-bf16, [1]=ints-are-i64
#define BAT8  24898    // 10240 u8: graph id per node
#define W1F_  27458    // 160*128 fp32
#define B1F_  47938
#define G1F_  48066
#define BE1F_ 48194
#define W2F_  48322    // 128*128
#define B2F_  64706
#define W3F_  64834    // 256*128
#define B3F_  97602
#define G3F_  97730
#define BE3F_ 97858
#define W4F_  97986    // 128*64
#define B4F_  106178   // 64
#define WSFIX 106242
#define YBF   106244   // bf16 y[10000][128] = 640,000 floats; byte 424,976 (16B aligned)
#define WSEND (YBF + 640000)

typedef __bf16 bf16x8 __attribute__((ext_vector_type(8)));
typedef float  f32x4  __attribute__((ext_vector_type(4)));

__device__ __forceinline__ float lrelu(float v) { return v > 0.f ? v : 0.01f * v; }

__device__ __forceinline__ bf16x8 cvt8(const float* p) {
  const f32x4 a0 = *(const f32x4*)p, a1 = *(const f32x4*)(p + 4);
  bf16x8 t;
  t[0]=(__bf16)a0[0]; t[1]=(__bf16)a0[1]; t[2]=(__bf16)a0[2]; t[3]=(__bf16)a0[3];
  t[4]=(__bf16)a1[0]; t[5]=(__bf16)a1[1]; t[6]=(__bf16)a1[2]; t[7]=(__bf16)a1[3];
  return t;
}

// ---- K0: dtype sniff + zero accumulators ----
__global__ __launch_bounds__(256) void k_sniff(const unsigned* __restrict__ xw,
                                               const unsigned* __restrict__ ew,
                                               float* __restrict__ ws) {
  const int tid = threadIdx.x;
  for (int i = tid; i < 8512; i += 256) ws[i] = 0.f;
  if (tid < 64) {
    const unsigned w = xw[tid];
    const unsigned ex = (w >> 7) & 0xFFu;
    int cb = (ex >= 100u && ex <= 140u) ? 1 : 0;
    int ci = (ew[2 * tid + 1] == 0u) ? 1 : 0;
#pragma unroll
    for (int s = 1; s < 64; s <<= 1) { cb += __shfl_xor(cb, s); ci += __shfl_xor(ci, s); }
    if (tid == 0) { int* f = (int*)(ws + FLGF); f[0] = (cb >= 48); f[1] = (ci >= 60); }
  }
}

__device__ __forceinline__ void cpyw(float* dst, const void* src, int n, int isb,
                                     int gtid, int gs) {
  if (isb) { const __bf16* s = (const __bf16*)src;
    for (int i = gtid; i < n; i += gs) dst[i] = (float)s[i];
  } else { const float* s = (const float*)src;
    for (int i = gtid; i < n; i += gs) dst[i] = s[i]; }
}

// ---- K1: weights->fp32 in ws, bat8 table, per-graph edge-count hist ----
__global__ __launch_bounds__(256) void k_norm(
    const void* __restrict__ eidx, const void* __restrict__ batch,
    const void* W1, const void* b1, const void* g1, const void* be1,
    const void* W2, const void* b2, const void* W3, const void* b3,
    const void* g3, const void* be3, const void* W4, const void* b4,
    float* __restrict__ ws) {
  const int gtid = blockIdx.x * 256 + threadIdx.x;
  const int gs = gridDim.x * 256;
  const int* f = (const int*)(ws + FLGF);
  const int isb = f[0], isi = f[1];
  cpyw(ws + W1F_, W1, 160 * HID, isb, gtid, gs);
  cpyw(ws + B1F_, b1, HID, isb, gtid, gs);
  cpyw(ws + G1F_, g1, HID, isb, gtid, gs);
  cpyw(ws + BE1F_, be1, HID, isb, gtid, gs);
  cpyw(ws + W2F_, W2, HID * HID, isb, gtid, gs);
  cpyw(ws + B2F_, b2, HID, isb, gtid, gs);
  cpyw(ws + W3F_, W3, 256 * HID, isb, gtid, gs);
  cpyw(ws + B3F_, b3, HID, isb, gtid, gs);
  cpyw(ws + G3F_, g3, HID, isb, gtid, gs);
  cpyw(ws + BE3F_, be3, HID, isb, gtid, gs);
  cpyw(ws + W4F_, W4, HID * DOUT, isb, gtid, gs);
  cpyw(ws + B4F_, b4, DOUT, isb, gtid, gs);
  const int* bs = (const int*)batch;
  unsigned char* b8 = (unsigned char*)(ws + BAT8);
  for (int i = gtid; i < NNODES_; i += gs)
    b8[i] = (unsigned char)((isi ? bs[2 * i] : bs[i]) & 63);
  // edge-count histogram
  __shared__ int h[NG];
  if (threadIdx.x < NG) h[threadIdx.x] = 0;
  __syncthreads();
  const int* es = (const int*)eidx;
  for (int e = gtid; e < EE; e += gs) {
    int cl = isi ? es[2 * (EE + e)] : es[EE + e];
    cl = min(max(cl, 0), NNODES_ - 1);
    const int g = (isi ? bs[2 * cl] : bs[cl]) & 63;
    atomicAdd(&h[g], 1);
  }
  __syncthreads();
  if (threadIdx.x < NG && h[threadIdx.x])
    unsafeAtomicAdd(&ws[CNTF + threadIdx.x], (float)h[threadIdx.x]);
}

// ---- K2: per-graph node-feature sums (batch sorted) ----
__global__ __launch_bounds__(256) void k_gx(
    const void* __restrict__ x, const void* __restrict__ batch, float* __restrict__ ws) {
  const int b = blockIdx.x, tid = threadIdx.x;
  const int isb = ((const int*)(ws + FLGF))[0];
  const int isi = ((const int*)(ws + FLGF))[1];
  const int* bt = (const int*)batch;
#define BATV(i) ((isi ? bt[2 * (i)] : bt[(i)]) & 63)
  int lo = 0, hi = NNODES_;
  while (lo < hi) { int m = (lo + hi) >> 1; if (BATV(m) < b) lo = m + 1; else hi = m; }
  const int r0 = lo;
  hi = NNODES_;
  while (lo < hi) { int m = (lo + hi) >> 1; if (BATV(m) < b + 1) lo = m + 1; else hi = m; }
  const int r1 = lo;
#undef BATV
  const int c = tid & 127, half = tid >> 7;
  float acc = 0.f;
  if (isb) { const __bf16* xs = (const __bf16*)x;
    for (int r = r0 + half; r < r1; r += 2) acc += (float)xs[r * DN + c];
  } else { const float* xs = (const float*)x;
    for (int r = r0 + half; r < r1; r += 2) acc += xs[r * DN + c]; }
  __shared__ float red[256];
  red[tid] = acc;
  __syncthreads();
  if (tid < 128) ws[GXF + b * DN + tid] = red[tid] + red[tid + 128];
}

// ---- K3a: y = x @ W1x + b1  (node GEMM, output bf16 into ws) ----
__global__ __launch_bounds__(256) void k_y(float* __restrict__ ws, const void* __restrict__ x) {
  __shared__ __align__(16) __bf16 w1x[128 * 128];   // [n][k], 32KB
  const int tid = threadIdx.x;
  const int isb = ((const int*)(ws + FLGF))[0];
  for (int i = tid; i < 128 * 128; i += 256) {
    const int k = i >> 7, n = i & 127;
    w1x[n * 128 + k] = (__bf16)ws[W1F_ + k * HID + n];
  }
  __syncthreads();
  const int lane = tid & 63, wid = tid >> 6, ml = lane & 15, kg = lane >> 4;
  __bf16* ybf = (__bf16*)(ws + YBF);
  for (int t = blockIdx.x * 4 + wid; t < 625; t += 160 * 4) {
    const int n0 = t * 16;
    const int row = n0 + ml;
    bf16x8 af[4];
    if (isb) {
      const __bf16* xp = (const __bf16*)x + row * DN + kg * 8;
#pragma unroll
      for (int ks = 0; ks < 4; ++ks) af[ks] = *(const bf16x8*)(xp + ks * 32);
    } else {
      const float* xp = (const float*)x + row * DN + kg * 8;
#pragma unroll
      for (int ks = 0; ks < 4; ++ks) af[ks] = cvt8(xp + ks * 32);
    }
    f32x4 acc[8] = {{0,0,0,0},{0,0,0,0},{0,0,0,0},{0,0,0,0},
                    {0,0,0,0},{0,0,0,0},{0,0,0,0},{0,0,0,0}};
#pragma unroll
    for (int ks = 0; ks < 4; ++ks) {
#pragma unroll
      for (int nt = 0; nt < 8; ++nt) {
        const bf16x8 bfr = *(const bf16x8*)(w1x + (nt * 16 + ml) * 128 + ks * 32 + kg * 8);
        acc[nt] = __builtin_amdgcn_mfma_f32_16x16x32_bf16(af[ks], bfr, acc[nt], 0, 0, 0);
      }
    }
#pragma unroll
    for (int nt = 0; nt < 8; ++nt) {
      const int c = nt * 16 + ml;
      const float bias = ws[B1F_ + c];
#pragma unroll
      for (int q = 0; q < 4; ++q)
        ybf[(n0 + kg * 4 + q) * HID + c] = (__bf16)(acc[nt][q] + bias);
    }
  }
}

// ---- K3b: edge loop (fast): z=ea@W1e via MFMA, +y via identity-MFMA, scatter ----
__global__ __launch_bounds__(512) void k_edgef(float* __restrict__ ws,
                                               const void* __restrict__ ea,
                                               const void* __restrict__ eidx) {
  __shared__ __align__(16) float smem[NG * 132];    // 33,792B; head reused for w1e staging
  __shared__ float sstat[256];                      // block stats: [0..127]=s1, [128..255]=s2
  const int tid = threadIdx.x;
  const int* flg = (const int*)(ws + FLGF);
  const int isb = flg[0], isi = flg[1];
  __bf16* w1e = (__bf16*)smem;                      // [n][k] 128x32 bf16 = 8KB
  for (int i = tid; i < 32 * 128; i += 512) {
    const int k = i >> 7, n = i & 127;
    w1e[n * 32 + k] = (__bf16)ws[W1F_ + (128 + k) * HID + n];
  }
  __syncthreads();
  const int lane = tid & 63, wid = tid >> 6, ml = lane & 15, kg = lane >> 4;
  bf16x8 bfe[8];
#pragma unroll
  for (int nt = 0; nt < 8; ++nt)
    bfe[nt] = *(const bf16x8*)(w1e + (nt * 16 + ml) * 32 + kg * 8);
  bf16x8 idf;
#pragma unroll
  for (int j = 0; j < 8; ++j) idf[j] = (kg * 8 + j == ml) ? (__bf16)1.0f : (__bf16)0.0f;
  __syncthreads();
  for (int i = tid; i < NG * 132; i += 512) smem[i] = 0.f;
  for (int i = tid; i < 256; i += 512) sstat[i] = 0.f;
  __syncthreads();

  const int* ei32 = (const int*)eidx;
  const unsigned char* bat8 = (const unsigned char*)(ws + BAT8);
  const __bf16* ybf = (const __bf16*)(ws + YBF);
  float s1[8] = {0,0,0,0,0,0,0,0}, s2[8] = {0,0,0,0,0,0,0,0};

  for (int t = blockIdx.x * 8 + wid; t < NMT; t += FNB * 8) {
    const int em = t * 16 + ml;
    int r = isi ? ei32[2 * em] : ei32[em];
    r = min(max(r, 0), NNODES_ - 1);
    int egq[4];
#pragma unroll
    for (int q = 0; q < 4; ++q) {
      const int e2 = t * 16 + kg * 4 + q;
      int cq = isi ? ei32[2 * (EE + e2)] : ei32[EE + e2];
      cq = min(max(cq, 0), NNODES_ - 1);
      egq[q] = bat8[cq];
    }
    bf16x8 ae;
    if (isb) ae = *(const bf16x8*)((const __bf16*)ea + em * DE + kg * 8);
    else     ae = cvt8((const float*)ea + em * DE + kg * 8);
    f32x4 acc[8] = {{0,0,0,0},{0,0,0,0},{0,0,0,0},{0,0,0,0},
                    {0,0,0,0},{0,0,0,0},{0,0,0,0},{0,0,0,0}};
#pragma unroll
    for (int nt = 0; nt < 8; ++nt)
      acc[nt] = __builtin_amdgcn_mfma_f32_16x16x32_bf16(ae, bfe[nt], acc[nt], 0, 0, 0);
    const __bf16* yb = ybf + r * HID + (kg & 1) * 8;
#pragma unroll
    for (int nt = 0; nt < 8; ++nt) {
      const bf16x8 ay = *(const bf16x8*)(yb + nt * 16);
      acc[nt] = __builtin_amdgcn_mfma_f32_16x16x32_bf16(ay, idf, acc[nt], 0, 0, 0);
    }
#pragma unroll
    for (int nt = 0; nt < 8; ++nt) {
      const int c = nt * 16 + ml;
#pragma unroll
      for (int q = 0; q < 4; ++q) {
        const float v = lrelu(acc[nt][q]);
        s1[nt] += v;
        s2[nt] += v * v;
        unsafeAtomicAdd(&smem[egq[q] * 132 + c], v);
      }
    }
  }
#pragma unroll
  for (int nt = 0; nt < 8; ++nt) {
    float v1 = s1[nt], v2 = s2[nt];
    v1 += __shfl_xor(v1, 16); v1 += __shfl_xor(v1, 32);
    v2 += __shfl_xor(v2, 16); v2 += __shfl_xor(v2, 32);
    if (kg == 0) {
      unsafeAtomicAdd(&sstat[nt * 16 + ml], v1);
      unsafeAtomicAdd(&sstat[128 + nt * 16 + ml], v2);
    }
  }
  __syncthreads();
  for (int i = tid; i < NG * HID; i += 512)
    unsafeAtomicAdd(&ws[ACCF + i], smem[(i >> 7) * 132 + (i & 127)]);
  if (tid < 128) {
    unsafeAtomicAdd(&ws[S1F + tid], sstat[tid]);
    unsafeAtomicAdd(&ws[S2F + tid], sstat[128 + tid]);
  }
}

// ---- K3s: slow fallback (Round-3 structure, known correct) ----
__global__ __launch_bounds__(256) void k_edges_slow(
    float* __restrict__ ws, const void* __restrict__ x, const void* __restrict__ ea,
    const void* __restrict__ eidx) {
  __shared__ __align__(16) char smem[40960];
  float* lacc = (float*)smem;
  __bf16* w1t = (__bf16*)smem;
  const int tid = threadIdx.x;
  const int* flg = (const int*)(ws + FLGF);
  const int isb = flg[0], isi = flg[1];
  for (int i = tid; i < 160 * HID; i += 256) {
    const int k = i >> 7, n = i & 127;
    w1t[n * 160 + k] = (__bf16)ws[W1F_ + i];
  }
  __syncthreads();
  const int lane = tid & 63, wid = tid >> 6;
  const int ml = lane & 15, kg = lane >> 4;
  const int ch0 = (wid & 1) * 64;
  const int pair = blockIdx.x * 2 + (wid >> 1);
  bf16x8 bfr[5][4];
  float b1v[4];
#pragma unroll
  for (int nt = 0; nt < 4; ++nt) {
    const int n = ch0 + nt * 16 + ml;
    b1v[nt] = ws[B1F_ + n];
#pragma unroll
    for (int ks = 0; ks < 5; ++ks)
      bfr[ks][nt] = *(const bf16x8*)(w1t + n * 160 + ks * 32 + kg * 8);
  }
  __syncthreads();
  for (int i = tid; i < NG * 132; i += 256) lacc[i] = 0.f;
  __syncthreads();
  float s1a[4] = {0,0,0,0}, s2a[4] = {0,0,0,0};
  const int* ei32 = (const int*)eidx;
  const unsigned char* bat8 = (const unsigned char*)(ws + BAT8);
  for (int mt = pair; mt < NMT; mt += 2 * SLOWNB) {
    const int em = mt * 16 + ml;
    int r  = isi ? ei32[2 * em] : ei32[em];
    int cl = isi ? ei32[2 * (EE + em)] : ei32[EE + em];
    r  = min(max(r, 0), NNODES_ - 1);
    cl = min(max(cl, 0), NNODES_ - 1);
    const int gg = bat8[cl];
    f32x4 acc[4] = {{0,0,0,0},{0,0,0,0},{0,0,0,0},{0,0,0,0}};
#pragma unroll
    for (int ks = 0; ks < 4; ++ks) {
      bf16x8 afr;
      if (isb) afr = *(const bf16x8*)((const __bf16*)x + r * DN + ks * 32 + kg * 8);
      else     afr = cvt8((const float*)x + r * DN + ks * 32 + kg * 8);
#pragma unroll
      for (int nt = 0; nt < 4; ++nt)
        acc[nt] = __builtin_amdgcn_mfma_f32_16x16x32_bf16(afr, bfr[ks][nt], acc[nt], 0, 0, 0);
    }
    {
      bf16x8 t;
      if (isb) t = *(const bf16x8*)((const __bf16*)ea + em * DE + kg * 8);
      else     t = cvt8((const float*)ea + em * DE + kg * 8);
#pragma unroll
      for (int nt = 0; nt < 4; ++nt)
        acc[nt] = __builtin_amdgcn_mfma_f32_16x16x32_bf16(t, bfr[4][nt], acc[nt], 0, 0, 0);
    }
    int gR[4];
#pragma unroll
    for (int q = 0; q < 4; ++q) gR[q] = __shfl(gg, kg * 4 + q);
#pragma unroll
    for (int nt = 0; nt < 4; ++nt) {
      const int c = ch0 + nt * 16 + ml;
#pragma unroll
      for (int q = 0; q < 4; ++q) {
        const float v = lrelu(acc[nt][q] + b1v[nt]);
        s1a[nt] += v;
        s2a[nt] += v * v;
        unsafeAtomicAdd(&lacc[gR[q] * 132 + c], v);
      }
    }
  }
#pragma unroll
  for (int nt = 0; nt < 4; ++nt) {
    float v1 = s1a[nt], v2 = s2a[nt];
    v1 += __shfl_xor(v1, 16); v1 += __shfl_xor(v1, 32);
    v2 += __shfl_xor(v2, 16); v2 += __shfl_xor(v2, 32);
    if (lane < 16) {
      unsafeAtomicAdd(&ws[S1F + ch0 + nt * 16 + lane], v1);
      unsafeAtomicAdd(&ws[S2F + ch0 + nt * 16 + lane], v2);
    }
  }
  __syncthreads();
  for (int i = tid; i < NG * HID; i += 256)
    unsafeAtomicAdd(&ws[ACCF + i], lacc[(i >> 7) * 132 + (i & 127)]);
}

// ---- K4: per-graph BN1-affine, go GEMM, layer1 of MLP2 ----
__global__ __launch_bounds__(128) void k_graph(float* __restrict__ ws) {
  const int b = blockIdx.x, c = threadIdx.x;
  const float invE = 1.f / (float)EE;
  const float mu  = ws[S1F + c] * invE;
  const float var = ws[S2F + c] * invE - mu * mu;
  const float s   = ws[G1F_ + c] * rsqrtf(var + 1e-5f);
  const float t   = ws[BE1F_ + c] - mu * s;
  const float cb  = ws[CNTF + b];
  __shared__ float zsh[HID];
  __shared__ float gv[DN + HID];
  zsh[c] = s * ws[ACCF + b * HID + c] + cb * t;
  gv[c]  = ws[GXF + b * DN + c];
  __syncthreads();
  float a = cb * ws[B2F_ + c];
  for (int k = 0; k < HID; ++k) a += zsh[k] * ws[W2F_ + k * HID + c];
  gv[DN + c] = a;
  __syncthreads();
  float h = ws[B3F_ + c];
  for (int j = 0; j < DN + HID; ++j) h += gv[j] * ws[W3F_ + j * HID + c];
  ws[O1F + b * HID + c] = lrelu(h);
}

// ---- K5: BN over 64 graphs + final Lin(128,64) ----
__global__ __launch_bounds__(64) void k_out(const float* __restrict__ ws,
                                            void* __restrict__ out) {
  const int b = blockIdx.x, o = threadIdx.x;
  const int isb = ((const int*)(ws + FLGF))[0];
  __shared__ float zrow[HID];
  for (int cc = o; cc < HID; cc += 64) {
    float sm = 0.f, sq = 0.f;
    for (int r = 0; r < NG; ++r) { const float v = ws[O1F + r * HID + cc]; sm += v; sq += v * v; }
    const float mu  = sm * (1.f / NG);
    const float var = sq * (1.f / NG) - mu * mu;
    const float sc  = ws[G3F_ + cc] * rsqrtf(var + 1e-5f);
    zrow[cc] = ws[O1F + b * HID + cc] * sc + (ws[BE3F_ + cc] - mu * sc);
  }
  __syncthreads();
  float a = ws[B4F_ + o];
  for (int k = 0; k < HID; ++k) a += zrow[k] * ws[W4F_ + k * DOUT + o];
  if (isb) ((__bf16*)out)[b * DOUT + o] = (__bf16)a;
  else     ((float*)out)[b * DOUT + o] = a;
}

extern "C" void kernel_launch(void* const* d_in, const int* in_sizes, int n_in,
                              void* d_out, int out_size, void* d_ws, size_t ws_size,
                              hipStream_t stream) {
  float* ws = (float*)d_ws;
  const int use_y = (ws_size >= (size_t)WSEND * 4) ? 1 : 0;   // constant per session
  hipLaunchKernelGGL(k_sniff, dim3(1), dim3(256), 0, stream,
                     (const unsigned*)d_in[0], (const unsigned*)d_in[1], ws);
  hipLaunchKernelGGL(k_norm, dim3(256), dim3(256), 0, stream,
                     d_in[1], d_in[4],
                     d_in[5], d_in[6], d_in[7], d_in[8],
                     d_in[9], d_in[10], d_in[11], d_in[12],
                     d_in[13], d_in[14], d_in[15], d_in[16], ws);
  hipLaunchKernelGGL(k_gx, dim3(NG), dim3(256), 0, stream, d_in[0], d_in[4], ws);
  if (use_y) {
    hipLaunchKernelGGL(k_y, dim3(160), dim3(256), 0, stream, ws, d_in[0]);
    hipLaunchKernelGGL(k_edgef, dim3(FNB), dim3(512), 0, stream, ws, d_in[2], d_in[1]);
  } else {
    hipLaunchKernelGGL(k_edges_slow, dim3(SLOWNB), dim3(256), 0, stream,
                       ws, d_in[0], d_in[2], d_in[1]);
  }
  hipLaunchKernelGGL(k_graph, dim3(NG), dim3(128), 0, stream, ws);
  hipLaunchKernelGGL(k_out, dim3(NG), dim3(64), 0, stream, ws, d_out);
}

// Round 5
// 668.482 us; speedup vs baseline: 1.0006x; 1.0006x over previous
//
#include <hip/hip_runtime.h>

#define EE      640000
#define NNODES_ 10000
#define NG      64
#define DN      128
#define DE      32
#define HID     128
#define DOUT    64
#define NMT     (EE / 16)
#define SLOWNB  768
#define FNB     768

// ---- workspace float-element offsets ----
#define ACCF  0        // [64][128] per-graph sum of a
#define CNTF  8192     // [64] edge count per graph (fp32)
#define S1F   8256     // [128] global sum(a)
#define S2F   8384     // [128] global sum(a^2)
#define GXF   8512     // [64][128] per-graph node sums
#define O1F   16704    // [64][128] mlp2 hidden
#define FLGF  24896    // int flags: [0]=floats-are-bf16, [1]=ints-are-i64
#define BAT8  24898    // 10240 u8: graph id per node
#define W1F_  27458    // 160*128 fp32
#define B1F_  47938
#define G1F_  48066
#define BE1F_ 48194
#define W2F_  48322    // 128*128
#define B2F_  64706
#define W3F_  64834    // 256*128
#define B3F_  97602
#define G3F_  97730
#define BE3F_ 97858
#define W4F_  97986    // 128*64
#define B4F_  106178   // 64
#define WSFIX 106242
#define YBF   106244   // bf16 y[10000][128] = 640,000 floats; byte 424,976 (16B aligned)
#define WSEND (YBF + 640000)

typedef __bf16 bf16x8 __attribute__((ext_vector_type(8)));
typedef float  f32x4  __attribute__((ext_vector_type(4)));

__device__ __forceinline__ float lrelu(float v) { return v > 0.f ? v : 0.01f * v; }

__device__ __forceinline__ bf16x8 cvt8(const float* p) {
  const f32x4 a0 = *(const f32x4*)p, a1 = *(const f32x4*)(p + 4);
  bf16x8 t;
  t[0]=(__bf16)a0[0]; t[1]=(__bf16)a0[1]; t[2]=(__bf16)a0[2]; t[3]=(__bf16)a0[3];
  t[4]=(__bf16)a1[0]; t[5]=(__bf16)a1[1]; t[6]=(__bf16)a1[2]; t[7]=(__bf16)a1[3];
  return t;
}

// ---- K0: dtype sniff + zero accumulators ----
__global__ __launch_bounds__(256) void k_sniff(const unsigned* __restrict__ xw,
                                               const unsigned* __restrict__ ew,
                                               float* __restrict__ ws) {
  const int tid = threadIdx.x;
  for (int i = tid; i < 8512; i += 256) ws[i] = 0.f;
  if (tid < 64) {
    const unsigned w = xw[tid];
    const unsigned ex = (w >> 7) & 0xFFu;
    int cb = (ex >= 100u && ex <= 140u) ? 1 : 0;
    int ci = (ew[2 * tid + 1] == 0u) ? 1 : 0;
#pragma unroll
    for (int s = 1; s < 64; s <<= 1) { cb += __shfl_xor(cb, s); ci += __shfl_xor(ci, s); }
    if (tid == 0) { int* f = (int*)(ws + FLGF); f[0] = (cb >= 48); f[1] = (ci >= 60); }
  }
}

__device__ __forceinline__ void cpyw(float* dst, const void* src, int n, int isb,
                                     int gtid, int gs) {
  if (isb) { const __bf16* s = (const __bf16*)src;
    for (int i = gtid; i < n; i += gs) dst[i] = (float)s[i];
  } else { const float* s = (const float*)src;
    for (int i = gtid; i < n; i += gs) dst[i] = s[i]; }
}

// ---- K1: weights->fp32 in ws, bat8 table, per-graph edge-count hist ----
__global__ __launch_bounds__(256) void k_norm(
    const void* __restrict__ eidx, const void* __restrict__ batch,
    const void* W1, const void* b1, const void* g1, const void* be1,
    const void* W2, const void* b2, const void* W3, const void* b3,
    const void* g3, const void* be3, const void* W4, const void* b4,
    float* __restrict__ ws) {
  const int gtid = blockIdx.x * 256 + threadIdx.x;
  const int gs = gridDim.x * 256;
  const int* f = (const int*)(ws + FLGF);
  const int isb = f[0], isi = f[1];
  cpyw(ws + W1F_, W1, 160 * HID, isb, gtid, gs);
  cpyw(ws + B1F_, b1, HID, isb, gtid, gs);
  cpyw(ws + G1F_, g1, HID, isb, gtid, gs);
  cpyw(ws + BE1F_, be1, HID, isb, gtid, gs);
  cpyw(ws + W2F_, W2, HID * HID, isb, gtid, gs);
  cpyw(ws + B2F_, b2, HID, isb, gtid, gs);
  cpyw(ws + W3F_, W3, 256 * HID, isb, gtid, gs);
  cpyw(ws + B3F_, b3, HID, isb, gtid, gs);
  cpyw(ws + G3F_, g3, HID, isb, gtid, gs);
  cpyw(ws + BE3F_, be3, HID, isb, gtid, gs);
  cpyw(ws + W4F_, W4, HID * DOUT, isb, gtid, gs);
  cpyw(ws + B4F_, b4, DOUT, isb, gtid, gs);
  const int* bs = (const int*)batch;
  unsigned char* b8 = (unsigned char*)(ws + BAT8);
  for (int i = gtid; i < NNODES_; i += gs)
    b8[i] = (unsigned char)((isi ? bs[2 * i] : bs[i]) & 63);
  // edge-count histogram
  __shared__ int h[NG];
  if (threadIdx.x < NG) h[threadIdx.x] = 0;
  __syncthreads();
  const int* es = (const int*)eidx;
  for (int e = gtid; e < EE; e += gs) {
    int cl = isi ? es[2 * (EE + e)] : es[EE + e];
    cl = min(max(cl, 0), NNODES_ - 1);
    const int g = (isi ? bs[2 * cl] : bs[cl]) & 63;
    atomicAdd(&h[g], 1);
  }
  __syncthreads();
  if (threadIdx.x < NG && h[threadIdx.x])
    unsafeAtomicAdd(&ws[CNTF + threadIdx.x], (float)h[threadIdx.x]);
}

// ---- K2: per-graph node-feature sums (batch sorted) ----
__global__ __launch_bounds__(256) void k_gx(
    const void* __restrict__ x, const void* __restrict__ batch, float* __restrict__ ws) {
  const int b = blockIdx.x, tid = threadIdx.x;
  const int isb = ((const int*)(ws + FLGF))[0];
  const int isi = ((const int*)(ws + FLGF))[1];
  const int* bt = (const int*)batch;
#define BATV(i) ((isi ? bt[2 * (i)] : bt[(i)]) & 63)
  int lo = 0, hi = NNODES_;
  while (lo < hi) { int m = (lo + hi) >> 1; if (BATV(m) < b) lo = m + 1; else hi = m; }
  const int r0 = lo;
  hi = NNODES_;
  while (lo < hi) { int m = (lo + hi) >> 1; if (BATV(m) < b + 1) lo = m + 1; else hi = m; }
  const int r1 = lo;
#undef BATV
  const int c = tid & 127, half = tid >> 7;
  float acc = 0.f;
  if (isb) { const __bf16* xs = (const __bf16*)x;
    for (int r = r0 + half; r < r1; r += 2) acc += (float)xs[r * DN + c];
  } else { const float* xs = (const float*)x;
    for (int r = r0 + half; r < r1; r += 2) acc += xs[r * DN + c]; }
  __shared__ float red[256];
  red[tid] = acc;
  __syncthreads();
  if (tid < 128) ws[GXF + b * DN + tid] = red[tid] + red[tid + 128];
}

// ---- K3a: y = x @ W1x + b1  (node GEMM, output bf16 into ws) ----
__global__ __launch_bounds__(256) void k_y(float* __restrict__ ws, const void* __restrict__ x) {
  __shared__ __align__(16) __bf16 w1x[128 * 128];   // [n][k], 32KB
  const int tid = threadIdx.x;
  const int isb = ((const int*)(ws + FLGF))[0];
  for (int i = tid; i < 128 * 128; i += 256) {
    const int k = i >> 7, n = i & 127;
    w1x[n * 128 + k] = (__bf16)ws[W1F_ + k * HID + n];
  }
  __syncthreads();
  const int lane = tid & 63, wid = tid >> 6, ml = lane & 15, kg = lane >> 4;
  __bf16* ybf = (__bf16*)(ws + YBF);
  for (int t = blockIdx.x * 4 + wid; t < 625; t += 160 * 4) {
    const int n0 = t * 16;
    const int row = n0 + ml;
    bf16x8 af[4];
    if (isb) {
      const __bf16* xp = (const __bf16*)x + row * DN + kg * 8;
#pragma unroll
      for (int ks = 0; ks < 4; ++ks) af[ks] = *(const bf16x8*)(xp + ks * 32);
    } else {
      const float* xp = (const float*)x + row * DN + kg * 8;
#pragma unroll
      for (int ks = 0; ks < 4; ++ks) af[ks] = cvt8(xp + ks * 32);
    }
    f32x4 acc[8] = {{0,0,0,0},{0,0,0,0},{0,0,0,0},{0,0,0,0},
                    {0,0,0,0},{0,0,0,0},{0,0,0,0},{0,0,0,0}};
#pragma unroll
    for (int ks = 0; ks < 4; ++ks) {
#pragma unroll
      for (int nt = 0; nt < 8; ++nt) {
        const bf16x8 bfr = *(const bf16x8*)(w1x + (nt * 16 + ml) * 128 + ks * 32 + kg * 8);
        acc[nt] = __builtin_amdgcn_mfma_f32_16x16x32_bf16(af[ks], bfr, acc[nt], 0, 0, 0);
      }
    }
#pragma unroll
    for (int nt = 0; nt < 8; ++nt) {
      const int c = nt * 16 + ml;
      const float bias = ws[B1F_ + c];
#pragma unroll
      for (int q = 0; q < 4; ++q)
        ybf[(n0 + kg * 4 + q) * HID + c] = (__bf16)(acc[nt][q] + bias);
    }
  }
}

// ---- K3b: edge loop (fast): z=ea@W1e via MFMA, +y via identity-MFMA, scatter ----
__global__ __launch_bounds__(512) void k_edgef(float* __restrict__ ws,
                                               const void* __restrict__ ea,
                                               const void* __restrict__ eidx) {
  __shared__ __align__(16) float smem[NG * 132];    // 33,792B; head reused for w1e staging
  __shared__ float sstat[256];                      // block stats: [0..127]=s1, [128..255]=s2
  const int tid = threadIdx.x;
  const int* flg = (const int*)(ws + FLGF);
  const int isb = flg[0], isi = flg[1];
  __bf16* w1e = (__bf16*)smem;                      // [n][k] 128x32 bf16 = 8KB
  for (int i = tid; i < 32 * 128; i += 512) {
    const int k = i >> 7, n = i & 127;
    w1e[n * 32 + k] = (__bf16)ws[W1F_ + (128 + k) * HID + n];
  }
  __syncthreads();
  const int lane = tid & 63, wid = tid >> 6, ml = lane & 15, kg = lane >> 4;
  bf16x8 bfe[8];
#pragma unroll
  for (int nt = 0; nt < 8; ++nt)
    bfe[nt] = *(const bf16x8*)(w1e + (nt * 16 + ml) * 32 + kg * 8);
  bf16x8 idf;
#pragma unroll
  for (int j = 0; j < 8; ++j) idf[j] = (kg * 8 + j == ml) ? (__bf16)1.0f : (__bf16)0.0f;
  __syncthreads();
  for (int i = tid; i < NG * 132; i += 512) smem[i] = 0.f;
  for (int i = tid; i < 256; i += 512) sstat[i] = 0.f;
  __syncthreads();

  const int* ei32 = (const int*)eidx;
  const unsigned char* bat8 = (const unsigned char*)(ws + BAT8);
  const __bf16* ybf = (const __bf16*)(ws + YBF);
  float s1[8] = {0,0,0,0,0,0,0,0}, s2[8] = {0,0,0,0,0,0,0,0};

  for (int t = blockIdx.x * 8 + wid; t < NMT; t += FNB * 8) {
    const int em = t * 16 + ml;
    int r = isi ? ei32[2 * em] : ei32[em];
    r = min(max(r, 0), NNODES_ - 1);
    int egq[4];
#pragma unroll
    for (int q = 0; q < 4; ++q) {
      const int e2 = t * 16 + kg * 4 + q;
      int cq = isi ? ei32[2 * (EE + e2)] : ei32[EE + e2];
      cq = min(max(cq, 0), NNODES_ - 1);
      egq[q] = bat8[cq];
    }
    bf16x8 ae;
    if (isb) ae = *(const bf16x8*)((const __bf16*)ea + em * DE + kg * 8);
    else     ae = cvt8((const float*)ea + em * DE + kg * 8);
    f32x4 acc[8] = {{0,0,0,0},{0,0,0,0},{0,0,0,0},{0,0,0,0},
                    {0,0,0,0},{0,0,0,0},{0,0,0,0},{0,0,0,0}};
#pragma unroll
    for (int nt = 0; nt < 8; ++nt)
      acc[nt] = __builtin_amdgcn_mfma_f32_16x16x32_bf16(ae, bfe[nt], acc[nt], 0, 0, 0);
    const __bf16* yb = ybf + r * HID + (kg & 1) * 8;
#pragma unroll
    for (int nt = 0; nt < 8; ++nt) {
      const bf16x8 ay = *(const bf16x8*)(yb + nt * 16);
      acc[nt] = __builtin_amdgcn_mfma_f32_16x16x32_bf16(ay, idf, acc[nt], 0, 0, 0);
    }
#pragma unroll
    for (int nt = 0; nt < 8; ++nt) {
      const int c = nt * 16 + ml;
#pragma unroll
      for (int q = 0; q < 4; ++q) {
        const float v = lrelu(acc[nt][q]);
        s1[nt] += v;
        s2[nt] += v * v;
        atomicAdd(&smem[egq[q] * 132 + c], v);   // native ds_add_f32 (LDS)
      }
    }
  }
#pragma unroll
  for (int nt = 0; nt < 8; ++nt) {
    float v1 = s1[nt], v2 = s2[nt];
    v1 += __shfl_xor(v1, 16); v1 += __shfl_xor(v1, 32);
    v2 += __shfl_xor(v2, 16); v2 += __shfl_xor(v2, 32);
    if (kg == 0) {
      atomicAdd(&sstat[nt * 16 + ml], v1);       // LDS
      atomicAdd(&sstat[128 + nt * 16 + ml], v2); // LDS
    }
  }
  __syncthreads();
  for (int i = tid; i < NG * HID; i += 512)
    unsafeAtomicAdd(&ws[ACCF + i], smem[(i >> 7) * 132 + (i & 127)]);
  if (tid < 128) {
    unsafeAtomicAdd(&ws[S1F + tid], sstat[tid]);
    unsafeAtomicAdd(&ws[S2F + tid], sstat[128 + tid]);
  }
}

// ---- K3s: slow fallback (Round-3 structure, known correct) ----
__global__ __launch_bounds__(256) void k_edges_slow(
    float* __restrict__ ws, const void* __restrict__ x, const void* __restrict__ ea,
    const void* __restrict__ eidx) {
  __shared__ __align__(16) char smem[40960];
  float* lacc = (float*)smem;
  __bf16* w1t = (__bf16*)smem;
  const int tid = threadIdx.x;
  const int* flg = (const int*)(ws + FLGF);
  const int isb = flg[0], isi = flg[1];
  for (int i = tid; i < 160 * HID; i += 256) {
    const int k = i >> 7, n = i & 127;
    w1t[n * 160 + k] = (__bf16)ws[W1F_ + i];
  }
  __syncthreads();
  const int lane = tid & 63, wid = tid >> 6;
  const int ml = lane & 15, kg = lane >> 4;
  const int ch0 = (wid & 1) * 64;
  const int pair = blockIdx.x * 2 + (wid >> 1);
  bf16x8 bfr[5][4];
  float b1v[4];
#pragma unroll
  for (int nt = 0; nt < 4; ++nt) {
    const int n = ch0 + nt * 16 + ml;
    b1v[nt] = ws[B1F_ + n];
#pragma unroll
    for (int ks = 0; ks < 5; ++ks)
      bfr[ks][nt] = *(const bf16x8*)(w1t + n * 160 + ks * 32 + kg * 8);
  }
  __syncthreads();
  for (int i = tid; i < NG * 132; i += 256) lacc[i] = 0.f;
  __syncthreads();
  float s1a[4] = {0,0,0,0}, s2a[4] = {0,0,0,0};
  const int* ei32 = (const int*)eidx;
  const unsigned char* bat8 = (const unsigned char*)(ws + BAT8);
  for (int mt = pair; mt < NMT; mt += 2 * SLOWNB) {
    const int em = mt * 16 + ml;
    int r  = isi ? ei32[2 * em] : ei32[em];
    int cl = isi ? ei32[2 * (EE + em)] : ei32[EE + em];
    r  = min(max(r, 0), NNODES_ - 1);
    cl = min(max(cl, 0), NNODES_ - 1);
    const int gg = bat8[cl];
    f32x4 acc[4] = {{0,0,0,0},{0,0,0,0},{0,0,0,0},{0,0,0,0}};
#pragma unroll
    for (int ks = 0; ks < 4; ++ks) {
      bf16x8 afr;
      if (isb) afr = *(const bf16x8*)((const __bf16*)x + r * DN + ks * 32 + kg * 8);
      else     afr = cvt8((const float*)x + r * DN + ks * 32 + kg * 8);
#pragma unroll
      for (int nt = 0; nt < 4; ++nt)
        acc[nt] = __builtin_amdgcn_mfma_f32_16x16x32_bf16(afr, bfr[ks][nt], acc[nt], 0, 0, 0);
    }
    {
      bf16x8 t;
      if (isb) t = *(const bf16x8*)((const __bf16*)ea + em * DE + kg * 8);
      else     t = cvt8((const float*)ea + em * DE + kg * 8);
#pragma unroll
      for (int nt = 0; nt < 4; ++nt)
        acc[nt] = __builtin_amdgcn_mfma_f32_16x16x32_bf16(t, bfr[4][nt], acc[nt], 0, 0, 0);
    }
    int gR[4];
#pragma unroll
    for (int q = 0; q < 4; ++q) gR[q] = __shfl(gg, kg * 4 + q);
#pragma unroll
    for (int nt = 0; nt < 4; ++nt) {
      const int c = ch0 + nt * 16 + ml;
#pragma unroll
      for (int q = 0; q < 4; ++q) {
        const float v = lrelu(acc[nt][q] + b1v[nt]);
        s1a[nt] += v;
        s2a[nt] += v * v;
        atomicAdd(&lacc[gR[q] * 132 + c], v);    // native ds_add_f32 (LDS)
      }
    }
  }
#pragma unroll
  for (int nt = 0; nt < 4; ++nt) {
    float v1 = s1a[nt], v2 = s2a[nt];
    v1 += __shfl_xor(v1, 16); v1 += __shfl_xor(v1, 32);
    v2 += __shfl_xor(v2, 16); v2 += __shfl_xor(v2, 32);
    if (lane < 16) {
      unsafeAtomicAdd(&ws[S1F + ch0 + nt * 16 + lane], v1);
      unsafeAtomicAdd(&ws[S2F + ch0 + nt * 16 + lane], v2);
    }
  }
  __syncthreads();
  for (int i = tid; i < NG * HID; i += 256)
    unsafeAtomicAdd(&ws[ACCF + i], lacc[(i >> 7) * 132 + (i & 127)]);
}

// ---- K4: per-graph BN1-affine, go GEMM, layer1 of MLP2 ----
__global__ __launch_bounds__(128) void k_graph(float* __restrict__ ws) {
  const int b = blockIdx.x, c = threadIdx.x;
  const float invE = 1.f / (float)EE;
  const float mu  = ws[S1F + c] * invE;
  const float var = ws[S2F + c] * invE - mu * mu;
  const float s   = ws[G1F_ + c] * rsqrtf(var + 1e-5f);
  const float t   = ws[BE1F_ + c] - mu * s;
  const float cb  = ws[CNTF + b];
  __shared__ float zsh[HID];
  __shared__ float gv[DN + HID];
  zsh[c] = s * ws[ACCF + b * HID + c] + cb * t;
  gv[c]  = ws[GXF + b * DN + c];
  __syncthreads();
  float a = cb * ws[B2F_ + c];
  for (int k = 0; k < HID; ++k) a += zsh[k] * ws[W2F_ + k * HID + c];
  gv[DN + c] = a;
  __syncthreads();
  float h = ws[B3F_ + c];
  for (int j = 0; j < DN + HID; ++j) h += gv[j] * ws[W3F_ + j * HID + c];
  ws[O1F + b * HID + c] = lrelu(h);
}

// ---- K5: BN over 64 graphs + final Lin(128,64) ----
__global__ __launch_bounds__(64) void k_out(const float* __restrict__ ws,
                                            void* __restrict__ out) {
  const int b = blockIdx.x, o = threadIdx.x;
  const int isb = ((const int*)(ws + FLGF))[0];
  __shared__ float zrow[HID];
  for (int cc = o; cc < HID; cc += 64) {
    float sm = 0.f, sq = 0.f;
    for (int r = 0; r < NG; ++r) { const float v = ws[O1F + r * HID + cc]; sm += v; sq += v * v; }
    const float mu  = sm * (1.f / NG);
    const float var = sq * (1.f / NG) - mu * mu;
    const float sc  = ws[G3F_ + cc] * rsqrtf(var + 1e-5f);
    zrow[cc] = ws[O1F + b * HID + cc] * sc + (ws[BE3F_ + cc] - mu * sc);
  }
  __syncthreads();
  float a = ws[B4F_ + o];
  for (int k = 0; k < HID; ++k) a += zrow[k] * ws[W4F_ + k * DOUT + o];
  if (isb) ((__bf16*)out)[b * DOUT + o] = (__bf16)a;
  else     ((float*)out)[b * DOUT + o] = a;
}

extern "C" void kernel_launch(void* const* d_in, const int* in_sizes, int n_in,
                              void* d_out, int out_size, void* d_ws, size_t ws_size,
                              hipStream_t stream) {
  float* ws = (float*)d_ws;
  const int use_y = (ws_size >= (size_t)WSEND * 4) ? 1 : 0;   // constant per session
  hipLaunchKernelGGL(k_sniff, dim3(1), dim3(256), 0, stream,
                     (const unsigned*)d_in[0], (const unsigned*)d_in[1], ws);
  hipLaunchKernelGGL(k_norm, dim3(256), dim3(256), 0, stream,
                     d_in[1], d_in[4],
                     d_in[5], d_in[6], d_in[7], d_in[8],
                     d_in[9], d_in[10], d_in[11], d_in[12],
                     d_in[13], d_in[14], d_in[15], d_in[16], ws);
  hipLaunchKernelGGL(k_gx, dim3(NG), dim3(256), 0, stream, d_in[0], d_in[4], ws);
  if (use_y) {
    hipLaunchKernelGGL(k_y, dim3(160), dim3(256), 0, stream, ws, d_in[0]);
    hipLaunchKernelGGL(k_edgef, dim3(FNB), dim3(512), 0, stream, ws, d_in[2], d_in[1]);
  } else {
    hipLaunchKernelGGL(k_edges_slow, dim3(SLOWNB), dim3(256), 0, stream,
                       ws, d_in[0], d_in[2], d_in[1]);
  }
  hipLaunchKernelGGL(k_graph, dim3(NG), dim3(128), 0, stream, ws);
  hipLaunchKernelGGL(k_out, dim3(NG), dim3(64), 0, stream, ws, d_out);
}